// Round 5
// baseline (382.045 us; speedup 1.0000x reference)
//
#include <hip/hip_runtime.h>
#include <cstdint>
#include <math.h>

typedef __attribute__((ext_vector_type(8))) __bf16 bf16x8;
typedef __attribute__((ext_vector_type(4))) float f32x4;
typedef unsigned short ushort_t;

__device__ __forceinline__ ushort_t f2bf(float f) {
    uint32_t u = __float_as_uint(f);
    u += 0x7fff + ((u >> 16) & 1);   // RNE
    return (ushort_t)(u >> 16);
}

// tanh-form gelu: max dev from exact erf-gelu ~3e-3 (<< 7e-2 threshold)
__device__ __forceinline__ float gelu_fast(float x) {
    float u = x * (0.7978845608f + 0.0356774081f * x * x);
    float e = __expf(2.0f * u);
    float th = 1.0f - 2.0f / (e + 1.0f);
    return 0.5f * x * (1.0f + th);
}

__device__ __forceinline__ float gelu_exact(float v) {
    return 0.5f * v * (1.0f + erff(v * 0.70710678118654752440f));
}

// ---------------- K_A: per-chunk expert histogram (blocks<nchunks) + W1/W2 bf16 convert ----
__global__ void histo_convw_kernel(const int* __restrict__ tm, int* __restrict__ cnt,
                                   int nchunks,
                                   const float* __restrict__ s1, const float* __restrict__ s2,
                                   ushort_t* __restrict__ d1, ushort_t* __restrict__ d2,
                                   int n4) {
    if (blockIdx.x < (unsigned)nchunks) {
        __shared__ int h[4];
        if (threadIdx.x < 4) h[threadIdx.x] = 0;
        __syncthreads();
        int e = tm[blockIdx.x * 256 + threadIdx.x];
        atomicAdd(&h[e], 1);
        __syncthreads();
        if (threadIdx.x < 4) cnt[blockIdx.x * 4 + threadIdx.x] = h[threadIdx.x];
    } else {
        const int stride = (gridDim.x - nchunks) * 256;
        for (int i = (blockIdx.x - nchunks) * 256 + threadIdx.x; i < 2 * n4; i += stride) {
            const float* src; ushort_t* dst; int k;
            if (i < n4) { src = s1; dst = d1; k = i; }
            else        { src = s2; dst = d2; k = i - n4; }
            const float4 v = ((const float4*)src)[k];
            ushort4 o;
            o.x = f2bf(v.x); o.y = f2bf(v.y); o.z = f2bf(v.z); o.w = f2bf(v.w);
            ((ushort4*)dst)[k] = o;
        }
    }
}

// ---------------- K_B: scan chunk histograms -> global chunk offsets + meta + pad fill -----
// meta: [e]=cnt  [4+e]=row off (128-aligned)  [8+e]=acnt  [12+e]=mtiles
//       [16+e]=xoff(elems)  [20+e]=hoff(elems)  [24+k]=g1 start (expert 3-k)
//       [28]=rows total  [29]=T1  [32+k]=g2 start (expert 3-k)  [36]=T2
//       [48]=tile counter GEMM1  [49]=tile counter GEMM2
// GEMM2 e3 region is DOUBLED (split-K x2: entry = tile*2 + khalf).
__global__ void meta_kernel(int* __restrict__ meta, int* __restrict__ cnt,
                            int* __restrict__ sidx, int nchunks, int D, int H) {
    __shared__ int tot[4];
    __shared__ int soff_s[4];
    const int t = threadIdx.x;
    const int e = t >> 6;        // wave e handles expert e
    const int c0 = t & 63;
    int carry = 0;
    for (int base = 0; base < nchunks; base += 64) {
        int c = base + c0;
        int v = (c < nchunks) ? cnt[c * 4 + e] : 0;
        int s = v;
#pragma unroll
        for (int d = 1; d < 64; d <<= 1) {
            int y = __shfl_up(s, d);
            if (c0 >= d) s += y;
        }
        if (c < nchunks) cnt[c * 4 + e] = s - v + carry;   // expert-local exclusive
        carry += __shfl(s, 63);
    }
    if (c0 == 0) tot[e] = carry;
    __syncthreads();
    if (t == 0) {
        int off = 0, xoff = 0, hoff = 0;
        for (int ee = 0; ee < 4; ee++) {
            int c = tot[ee];
            int ac = (c + 127) & ~127;
            meta[ee] = c; meta[4 + ee] = off; meta[8 + ee] = ac; meta[12 + ee] = ac >> 7;
            meta[16 + ee] = xoff; meta[20 + ee] = hoff;
            soff_s[ee] = off;
            off += ac; xoff += ac * (D >> (3 - ee)); hoff += ac * (H >> (3 - ee));
        }
        meta[28] = off;
        int a = 0, b = 0;
        for (int k = 0; k < 4; k++) {     // heavy expert first
            int ee = 3 - k;
            meta[24 + k] = a; a += meta[12 + ee] * ((H >> (3 - ee)) >> 7);
            meta[32 + k] = b; b += meta[12 + ee] * (D >> 7) * (ee == 3 ? 2 : 1);
        }
        meta[29] = a; meta[36] = b;
        meta[48] = 0;                     // dynamic tile counters
        meta[49] = 0;
    }
    __syncthreads();
    for (int base = 0; base < 64 * ((nchunks + 63) / 64); base += 64) {
        int c = base + c0;
        if (c < nchunks) cnt[c * 4 + e] += soff_s[e];      // -> global start per (chunk,e)
    }
    for (int ee = 0; ee < 4; ee++) {                        // pad slots -> -1
        int s0 = soff_s[ee] + tot[ee];
        int n = meta[8 + ee] - tot[ee];
        for (int i = t; i < n; i += 256) sidx[s0 + i] = -1;
    }
}

// ---------------- K_C: stable placement via intra-chunk rank ----------------
__global__ void place_kernel(const int* __restrict__ tm, const int* __restrict__ cofs,
                             int* __restrict__ sidx) {
    __shared__ unsigned char se[256];
    const int c = blockIdx.x;
    const int t = threadIdx.x;
    const int tok = c * 256 + t;
    const int e = tm[tok];
    se[t] = (unsigned char)e;
    __syncthreads();
    int rank = 0;
    for (int i = 0; i < t; i++) rank += (se[i] == (unsigned char)e);
    sidx[cofs[c * 4 + e] + rank] = tok;
}

// ---------------- K_D: sorted/truncated x convert + out := bias broadcast init -----
// (out init needed because GEMM2's split-K e3 tiles accumulate with atomicAdd)
__global__ void convert_x_sorted(const float* __restrict__ x,
                                 const int* __restrict__ meta,
                                 const int* __restrict__ sidx,
                                 ushort_t* __restrict__ xb,
                                 const float* __restrict__ b2,
                                 float* __restrict__ out,
                                 int Mtok, int D) {
    const int rows = meta[28];
    for (int p = blockIdx.x; p < rows; p += gridDim.x) {
        const int e = (p >= meta[5]) + (p >= meta[6]) + (p >= meta[7]);
        const int off = meta[4 + e];
        const int din = D >> (3 - e);
        const int tok = sidx[p];
        ushort_t* dst = xb + (size_t)meta[16 + e] + (size_t)(p - off) * din;
        const int c = threadIdx.x * 4;
        if (c < din) {
            if (tok < 0) {
                *(ushort4*)(dst + c) = ushort4{0, 0, 0, 0};
            } else {
                const float4 v = *(const float4*)(x + (size_t)tok * D + c);
                ushort4 o;
                o.x = f2bf(v.x); o.y = f2bf(v.y); o.z = f2bf(v.z); o.w = f2bf(v.w);
                *(ushort4*)(dst + c) = o;
            }
        }
    }
    // out[tok][d] = b2[d] for all tokens (D is power-of-2 >= 1024 per shape gate)
    const int d4 = D >> 2;
    const int total4 = Mtok * d4;
    const float4* b24 = (const float4*)b2;
    float4* out4 = (float4*)out;
    for (int i = blockIdx.x * blockDim.x + threadIdx.x; i < total4;
         i += gridDim.x * blockDim.x)
        out4[i] = b24[i & (d4 - 1)];
}

// stage one 128x32 A-subtile and one 128x32 B-subtile into one LDS buffer.
// per wave: its 1KB quarter of each 4KB half (linear lane*16B layout).
__device__ __forceinline__ void stage4(const ushort_t* Ag, const ushort_t* Bg,
                                       int lda, int ldb,
                                       char* AsB, char* BsB, int ldsoff) {
    __builtin_amdgcn_global_load_lds(
        (__attribute__((address_space(1))) void*)(uintptr_t)Ag,
        (__attribute__((address_space(3))) void*)(AsB + ldsoff), 16, 0, 0);
    __builtin_amdgcn_global_load_lds(
        (__attribute__((address_space(1))) void*)(uintptr_t)(Ag + (size_t)64 * lda),
        (__attribute__((address_space(3))) void*)(AsB + 4096 + ldsoff), 16, 0, 0);
    __builtin_amdgcn_global_load_lds(
        (__attribute__((address_space(1))) void*)(uintptr_t)Bg,
        (__attribute__((address_space(3))) void*)(BsB + ldsoff), 16, 0, 0);
    __builtin_amdgcn_global_load_lds(
        (__attribute__((address_space(1))) void*)(uintptr_t)(Bg + (size_t)64 * ldb),
        (__attribute__((address_space(3))) void*)(BsB + 4096 + ldsoff), 16, 0, 0);
}

// ---------------- persistent per-expert GEMM: 4-wave, depth-2 counted pipeline,
// dynamic heavy-first tile counter, 2 LDS buffers (33KB -> 4 blocks/CU). ----------
// EPI==0: A=xb(lda=din) B=W1(ldb=D) K=din N=dh -> h=gelu(acc+b1) bf16, ldc=dh
// EPI==1: A=hb(lda=dh)  B=W2(ldb=H) K=dh  N=D -> out[sidx] scatter.
//         e3 entries are split-K x2 (entry=tile*2+kh): each half runs K/2 and
//         accumulates into bias-pre-initialized out via fp32 atomicAdd.
template <int EPI>
__global__ void gemm_sorted(const ushort_t* __restrict__ Abuf,
                            const ushort_t* __restrict__ Bw,
                            const float* __restrict__ bias,
                            const int* meta,            // NOT restrict: aliases tctr
                            const int* __restrict__ sidx,
                            ushort_t* __restrict__ hb,
                            float* __restrict__ out,
                            int* tctr,
                            int D, int H) {
    __shared__ ushort_t As[2][128 * 32];
    __shared__ ushort_t Bs[2][128 * 32];
    __shared__ int s_next;

    const int t    = threadIdx.x;
    const int wave = t >> 6;
    const int lane = t & 63;
    const int quad = lane >> 4;
    const int l16  = lane & 15;
    const int wm   = wave & 1;
    const int wn   = wave >> 1;
    const int srow = t >> 2;
    const int scol = (t & 3) * 8;
    const int ldsoff = wave * 64 * 16;

    const int* st = meta + (EPI == 0 ? 24 : 32);
    const int  T  = meta[EPI == 0 ? 29 : 36];

    while (true) {
        if (t == 0) s_next = atomicAdd(tctr, 1);
        __syncthreads();
        const int idx = s_next;
        if (idx >= T) break;

        const int k3 = (idx >= st[1]) + (idx >= st[2]) + (idx >= st[3]);
        const int e = 3 - k3;
        int local = idx - st[k3];
        int kh = 0;
        if (EPI == 1 && e == 3) { kh = local & 1; local >>= 1; }   // split-K x2
        const int mtiles = meta[12 + e];
        const int mt = local % mtiles;
        const int nt = local / mtiles;

        const int Kfull = (EPI == 0) ? (D >> (3 - e)) : (H >> (3 - e));
        const int Ksub  = (EPI == 1 && e == 3) ? (Kfull >> 1) : Kfull;
        const int Ne  = (EPI == 0) ? (H >> (3 - e)) : D;
        const int lda = Kfull;
        const int ldb = (EPI == 0) ? D : H;
        const int nb  = nt * 128;
        const int koff = kh * Ksub;
        const ushort_t* A = Abuf + (size_t)((EPI == 0) ? meta[16 + e] : meta[20 + e]);

        const ushort_t* Ag = A + (size_t)(mt * 128 + srow) * lda + scol + koff;
        const ushort_t* Bg = Bw + (size_t)(nb + srow) * ldb + scol + koff;

        const int nsteps = Ksub >> 5;   // >= 4 everywhere (min K chunk = 128)

        f32x4 acc[4][4] = {};

        // prologue: fill the 2-deep pipeline
        stage4(Ag,      Bg,      lda, ldb, (char*)As[0], (char*)Bs[0], ldsoff);
        stage4(Ag + 32, Bg + 32, lda, ldb, (char*)As[1], (char*)Bs[1], ldsoff);

        int cur = 0;
        for (int s = 0; s < nsteps; ++s) {
            // wait for OWN step-s loads (oldest 4); keep next step's 4 in flight
            if (nsteps - s > 1) { asm volatile("s_waitcnt vmcnt(4)" ::: "memory"); }
            else                { asm volatile("s_waitcnt vmcnt(0)" ::: "memory"); }
            __builtin_amdgcn_s_barrier();        // all waves' step-s loads landed
            asm volatile("" ::: "memory");

            bf16x8 af[4], bfr[4];
#pragma unroll
            for (int i = 0; i < 4; i++) {
                af[i]  = *(const bf16x8*)(As[cur] + (wm * 64 + i * 16 + l16) * 32 + quad * 8);
                bfr[i] = *(const bf16x8*)(Bs[cur] + (wn * 64 + i * 16 + l16) * 32 + quad * 8);
            }
            asm volatile("s_waitcnt lgkmcnt(0)" ::: "memory");  // this wave done reading
            __builtin_amdgcn_s_barrier();        // all waves done reading buf[cur]
            asm volatile("" ::: "memory");

            // refill freed buffer with step s+2 (stays in flight across barriers)
            if (s + 2 < nsteps)
                stage4(Ag + (size_t)(s + 2) * 32, Bg + (size_t)(s + 2) * 32,
                       lda, ldb, (char*)As[cur], (char*)Bs[cur], ldsoff);

#pragma unroll
            for (int i = 0; i < 4; i++)
#pragma unroll
                for (int j = 0; j < 4; j++)
                    acc[i][j] = __builtin_amdgcn_mfma_f32_16x16x32_bf16(af[i], bfr[j], acc[i][j], 0, 0, 0);

            cur ^= 1;
        }

        // epilogue: C/D layout col=lane&15, row=quad*4+reg
        const int colbase = nb + wn * 64 + l16;
        float bv[4];
#pragma unroll
        for (int j = 0; j < 4; j++) bv[j] = bias[colbase + j * 16];

#pragma unroll
        for (int i = 0; i < 4; i++) {
#pragma unroll
            for (int r = 0; r < 4; r++) {
                const int lrow = mt * 128 + wm * 64 + i * 16 + quad * 4 + r;
                if (EPI == 0) {
                    ushort_t* dst = hb + (size_t)meta[20 + e] + (size_t)lrow * Ne;
#pragma unroll
                    for (int j = 0; j < 4; j++)
                        dst[colbase + j * 16] = f2bf(gelu_fast(acc[i][j][r] + bv[j]));
                } else {
                    const int tok = sidx[meta[4 + e] + lrow];
                    if (tok >= 0) {
                        float* dst = out + (size_t)tok * D;
                        if (e == 3) {      // split-K half: bias already in out
#pragma unroll
                            for (int j = 0; j < 4; j++)
                                atomicAdd(&dst[colbase + j * 16], acc[i][j][r]);
                        } else {           // single writer: overwrite bias-init
#pragma unroll
                            for (int j = 0; j < 4; j++)
                                dst[colbase + j * 16] = acc[i][j][r] + bv[j];
                        }
                    }
                }
            }
        }
        __syncthreads();   // protect s_next + LDS before next tile
    }
}

// ---------------- fallback: naive fp32 per-token ----------------
__global__ void naive_kernel(const float* __restrict__ x, const int* __restrict__ tm,
                             const float* __restrict__ W1, const float* __restrict__ b1,
                             const float* __restrict__ W2, const float* __restrict__ b2,
                             float* __restrict__ out, int D, int Hdim) {
    const int t = blockIdx.x;
    const int m = tm[t];
    const int din = D >> (3 - m);
    const int dh = Hdim >> (3 - m);
    extern __shared__ float sm[];
    float* xs = sm;
    float* hs = sm + D;
    for (int i = threadIdx.x; i < din; i += blockDim.x) xs[i] = x[(size_t)t * D + i];
    __syncthreads();
    for (int h = threadIdx.x; h < dh; h += blockDim.x) {
        const float* w = W1 + (size_t)h * D;
        float a = b1[h];
        for (int d = 0; d < din; d++) a += xs[d] * w[d];
        hs[h] = gelu_exact(a);
    }
    __syncthreads();
    for (int d = threadIdx.x; d < D; d += blockDim.x) {
        const float* w = W2 + (size_t)d * Hdim;
        float a = b2[d];
        for (int h = 0; h < dh; h++) a += hs[h] * w[h];
        out[(size_t)t * D + d] = a;
    }
}

extern "C" void kernel_launch(void* const* d_in, const int* in_sizes, int n_in,
                              void* d_out, int out_size, void* d_ws, size_t ws_size,
                              hipStream_t stream) {
    const float* x  = (const float*)d_in[0];
    const int* tm   = (const int*)d_in[1];
    const float* W1 = (const float*)d_in[2];
    const float* b1 = (const float*)d_in[3];
    const float* W2 = (const float*)d_in[4];
    const float* b2 = (const float*)d_in[5];
    float* out = (float*)d_out;

    const int M    = in_sizes[1];
    const int Hdim = in_sizes[3];
    const int D    = in_sizes[0] / M;

    const int Mpad = M + 512;
    const int nchunks = M / 256;
    const size_t meta_sz = 256;
    const size_t cnt_sz  = ((size_t)nchunks * 4 * 4 + 255) & ~(size_t)255;
    const size_t sidx_sz = ((size_t)Mpad * 4 + 255) & ~(size_t)255;
    const size_t xb_sz   = (size_t)Mpad * D * 2;
    const size_t w1_sz   = (size_t)Hdim * D * 2;
    const size_t w2_sz   = (size_t)D * Hdim * 2;
    const size_t hb_sz   = (size_t)Mpad * Hdim * 2;
    const size_t need_sorted = meta_sz + cnt_sz + sidx_sz + xb_sz + w1_sz + w2_sz + hb_sz;

    const bool shape_ok = (M % 256 == 0) && (D % 128 == 0) && (Hdim % 128 == 0) &&
                          (D >= 1024) && (D <= 1024) && (Hdim >= 4096);

    if (shape_ok && ws_size >= need_sorted) {
        char* p = (char*)d_ws;
        int* meta     = (int*)p;        p += meta_sz;
        int* cnt      = (int*)p;        p += cnt_sz;
        int* sidx     = (int*)p;        p += sidx_sz;
        ushort_t* xb  = (ushort_t*)p;   p += xb_sz;
        ushort_t* w1b = (ushort_t*)p;   p += w1_sz;
        ushort_t* w2b = (ushort_t*)p;   p += w2_sz;
        ushort_t* hb  = (ushort_t*)p;

        const int n4w = Hdim * D / 4;
        histo_convw_kernel<<<nchunks + 2048, 256, 0, stream>>>(tm, cnt, nchunks,
                                                               W1, W2, w1b, w2b, n4w);
        meta_kernel<<<1, 256, 0, stream>>>(meta, cnt, sidx, nchunks, D, Hdim);
        place_kernel<<<nchunks, 256, 0, stream>>>(tm, cnt, sidx);
        convert_x_sorted<<<2048, 256, 0, stream>>>(x, meta, sidx, xb, b2, out, M, D);

        gemm_sorted<0><<<1024, 256, 0, stream>>>(xb, w1b, b1, meta, sidx, hb, nullptr,
                                                 meta + 48, D, Hdim);
        gemm_sorted<1><<<1024, 256, 0, stream>>>(hb, w2b, b2, meta, sidx, nullptr, out,
                                                 meta + 49, D, Hdim);
        return;
    }

    const size_t shmem = (size_t)(D + Hdim) * sizeof(float);
    naive_kernel<<<M, 256, shmem, stream>>>(x, tm, W1, b1, W2, b2, out, D, Hdim);
}

// Round 6
// 314.913 us; speedup vs baseline: 1.2132x; 1.2132x over previous
//
#include <hip/hip_runtime.h>
#include <cstdint>
#include <math.h>

typedef __attribute__((ext_vector_type(8))) __bf16 bf16x8;
typedef __attribute__((ext_vector_type(4))) float f32x4;
typedef unsigned short ushort_t;

__device__ __forceinline__ ushort_t f2bf(float f) {
    uint32_t u = __float_as_uint(f);
    u += 0x7fff + ((u >> 16) & 1);   // RNE
    return (ushort_t)(u >> 16);
}

// tanh-form gelu: max dev from exact erf-gelu ~3e-3 (<< 7e-2 threshold)
__device__ __forceinline__ float gelu_fast(float x) {
    float u = x * (0.7978845608f + 0.0356774081f * x * x);
    float e = __expf(2.0f * u);
    float th = 1.0f - 2.0f / (e + 1.0f);
    return 0.5f * x * (1.0f + th);
}

__device__ __forceinline__ float gelu_exact(float v) {
    return 0.5f * v * (1.0f + erff(v * 0.70710678118654752440f));
}

// ---------------- K_A: per-chunk expert histogram (blocks<nchunks) + W1/W2 bf16 convert ----
__global__ void histo_convw_kernel(const int* __restrict__ tm, int* __restrict__ cnt,
                                   int nchunks,
                                   const float* __restrict__ s1, const float* __restrict__ s2,
                                   ushort_t* __restrict__ d1, ushort_t* __restrict__ d2,
                                   int n4) {
    if (blockIdx.x < (unsigned)nchunks) {
        __shared__ int h[4];
        if (threadIdx.x < 4) h[threadIdx.x] = 0;
        __syncthreads();
        int e = tm[blockIdx.x * 256 + threadIdx.x];
        atomicAdd(&h[e], 1);
        __syncthreads();
        if (threadIdx.x < 4) cnt[blockIdx.x * 4 + threadIdx.x] = h[threadIdx.x];
    } else {
        const int stride = (gridDim.x - nchunks) * 256;
        for (int i = (blockIdx.x - nchunks) * 256 + threadIdx.x; i < 2 * n4; i += stride) {
            const float* src; ushort_t* dst; int k;
            if (i < n4) { src = s1; dst = d1; k = i; }
            else        { src = s2; dst = d2; k = i - n4; }
            const float4 v = ((const float4*)src)[k];
            ushort4 o;
            o.x = f2bf(v.x); o.y = f2bf(v.y); o.z = f2bf(v.z); o.w = f2bf(v.w);
            ((ushort4*)dst)[k] = o;
        }
    }
}

// ---------------- K_B: scan chunk histograms -> global chunk offsets + meta + pad fill -----
// meta: [e]=cnt  [4+e]=row off (128-aligned)  [8+e]=acnt  [12+e]=mtiles
//       [16+e]=xoff(elems)  [20+e]=hoff(elems)  [28]=rows total
//       [64 + x*8 + k] (k=0..3): XCD x GEMM1 chunk start for expert 3-k; [..+4]=T1_x
//       [128 + x*8 + k]: same for GEMM2; [..+4]=T2_x
// XCD-locality schedule: GEMM1 partitions N-tiles per XCD (B L2-resident),
// GEMM2 partitions M-tiles per XCD (A L2-resident).
__global__ void meta_kernel(int* __restrict__ meta, int* __restrict__ cnt,
                            int* __restrict__ sidx, int nchunks, int D, int H) {
    __shared__ int tot[4];
    __shared__ int soff_s[4];
    const int t = threadIdx.x;
    const int e = t >> 6;        // wave e handles expert e
    const int c0 = t & 63;
    int carry = 0;
    for (int base = 0; base < nchunks; base += 64) {
        int c = base + c0;
        int v = (c < nchunks) ? cnt[c * 4 + e] : 0;
        int s = v;
#pragma unroll
        for (int d = 1; d < 64; d <<= 1) {
            int y = __shfl_up(s, d);
            if (c0 >= d) s += y;
        }
        if (c < nchunks) cnt[c * 4 + e] = s - v + carry;   // expert-local exclusive
        carry += __shfl(s, 63);
    }
    if (c0 == 0) tot[e] = carry;
    __syncthreads();
    if (t == 0) {
        int off = 0, xoff = 0, hoff = 0;
        for (int ee = 0; ee < 4; ee++) {
            int c = tot[ee];
            int ac = (c + 127) & ~127;
            meta[ee] = c; meta[4 + ee] = off; meta[8 + ee] = ac; meta[12 + ee] = ac >> 7;
            meta[16 + ee] = xoff; meta[20 + ee] = hoff;
            soff_s[ee] = off;
            off += ac; xoff += ac * (D >> (3 - ee)); hoff += ac * (H >> (3 - ee));
        }
        meta[28] = off;
        // per-XCD chunk tables (heavy expert first within each XCD)
        const int nt2 = D >> 7;
        for (int x = 0; x < 8; x++) {
            int s1 = 0, s2 = 0;
            for (int k = 0; k < 4; k++) {
                int ee = 3 - k;
                int mtl = meta[12 + ee];
                meta[64 + x * 8 + k] = s1;
                int q = ((H >> (3 - ee)) >> 7) >> 3;           // ntiles1/8
                int c1 = q ? (mtl * q)
                           : ((x & 1) ? (mtl - (mtl >> 1)) : (mtl >> 1));
                s1 += c1;
                meta[128 + x * 8 + k] = s2;
                int qm = mtl >> 3, rm = mtl & 7;
                int cm = qm + ((x < rm) ? 1 : 0);
                s2 += cm * nt2;
            }
            meta[64 + x * 8 + 4] = s1;
            meta[128 + x * 8 + 4] = s2;
        }
    }
    __syncthreads();
    for (int base = 0; base < 64 * ((nchunks + 63) / 64); base += 64) {
        int c = base + c0;
        if (c < nchunks) cnt[c * 4 + e] += soff_s[e];      // -> global start per (chunk,e)
    }
    for (int ee = 0; ee < 4; ee++) {                        // pad slots -> -1
        int s0 = soff_s[ee] + tot[ee];
        int n = meta[8 + ee] - tot[ee];
        for (int i = t; i < n; i += 256) sidx[s0 + i] = -1;
    }
}

// ---------------- K_C: stable placement via ballot rank ----------------
__global__ void place_kernel(const int* __restrict__ tm, const int* __restrict__ cofs,
                             int* __restrict__ sidx) {
    __shared__ int wc[4][4];   // [wave][expert]
    const int c = blockIdx.x;
    const int t = threadIdx.x;
    const int wave = t >> 6;
    const int lane = t & 63;
    const int tok = c * 256 + t;
    const int e = tm[tok];
    unsigned long long bal[4];
#pragma unroll
    for (int v = 0; v < 4; v++) bal[v] = __ballot(e == v);
    if (lane < 4) wc[wave][lane] = __popcll(bal[lane]);
    __syncthreads();
    int pre = 0;
#pragma unroll
    for (int w = 0; w < 4; w++)
        if (w < wave) pre += wc[w][e];
    const unsigned long long lower = (1ull << lane) - 1ull;
    const int rank = pre + __popcll(bal[e] & lower);
    sidx[cofs[c * 4 + e] + rank] = tok;
}

// ---------------- K_D: sorted/truncated x convert (compacted, stride d_in(e)) -----
__global__ void convert_x_sorted(const float* __restrict__ x,
                                 const int* __restrict__ meta,
                                 const int* __restrict__ sidx,
                                 ushort_t* __restrict__ xb, int D) {
    const int rows = meta[28];
    for (int p = blockIdx.x; p < rows; p += gridDim.x) {
        const int e = (p >= meta[5]) + (p >= meta[6]) + (p >= meta[7]);
        const int off = meta[4 + e];
        const int din = D >> (3 - e);
        const int tok = sidx[p];
        ushort_t* dst = xb + (size_t)meta[16 + e] + (size_t)(p - off) * din;
        const int c = threadIdx.x * 4;
        if (c < din) {
            if (tok < 0) {
                *(ushort4*)(dst + c) = ushort4{0, 0, 0, 0};
            } else {
                const float4 v = *(const float4*)(x + (size_t)tok * D + c);
                ushort4 o;
                o.x = f2bf(v.x); o.y = f2bf(v.y); o.z = f2bf(v.z); o.w = f2bf(v.w);
                *(ushort4*)(dst + c) = o;
            }
        }
    }
}

// stage one 128x32 A-subtile and one 128x32 B-subtile into one LDS buffer.
// per wave: its 1KB quarter of each 4KB half (linear lane*16B layout).
__device__ __forceinline__ void stage4(const ushort_t* Ag, const ushort_t* Bg,
                                       int lda, int ldb,
                                       char* AsB, char* BsB, int ldsoff) {
    __builtin_amdgcn_global_load_lds(
        (__attribute__((address_space(1))) void*)(uintptr_t)Ag,
        (__attribute__((address_space(3))) void*)(AsB + ldsoff), 16, 0, 0);
    __builtin_amdgcn_global_load_lds(
        (__attribute__((address_space(1))) void*)(uintptr_t)(Ag + (size_t)64 * lda),
        (__attribute__((address_space(3))) void*)(AsB + 4096 + ldsoff), 16, 0, 0);
    __builtin_amdgcn_global_load_lds(
        (__attribute__((address_space(1))) void*)(uintptr_t)Bg,
        (__attribute__((address_space(3))) void*)(BsB + ldsoff), 16, 0, 0);
    __builtin_amdgcn_global_load_lds(
        (__attribute__((address_space(1))) void*)(uintptr_t)(Bg + (size_t)64 * ldb),
        (__attribute__((address_space(3))) void*)(BsB + 4096 + ldsoff), 16, 0, 0);
}

// ---------------- persistent per-expert GEMM: 4-wave, depth-3 counted pipeline
// (proven R2 core), XCD-locality static tile schedule. ----------
// EPI==0: A=xb(lda=din) B=W1(ldb=D) K=din N=dh -> h=gelu(acc+b1) bf16, ldc=dh
//         XCD x owns ntiles/8 N-panels (B stays in its L2); mt-major order so
//         q consecutive blocks (same CU-neighborhood) share one A-panel fetch.
// EPI==1: A=hb(lda=dh)  B=W2(ldb=H) K=dh  N=D -> out[sidx]=acc+b2 fp32 scatter
//         XCD x owns a bijective mtiles/8 chunk (A panels stay in its L2);
//         nt-outer order so concurrent blocks share one B-panel fetch.
template <int EPI>
__global__ void gemm_sorted(const ushort_t* __restrict__ Abuf,
                            const ushort_t* __restrict__ Bw,
                            const float* __restrict__ bias,
                            const int* __restrict__ meta,
                            const int* __restrict__ sidx,
                            ushort_t* __restrict__ hb,
                            float* __restrict__ out,
                            int D, int H) {
    __shared__ ushort_t As[3][128 * 32];
    __shared__ ushort_t Bs[3][128 * 32];

    const int t    = threadIdx.x;
    const int wave = t >> 6;
    const int lane = t & 63;
    const int quad = lane >> 4;
    const int l16  = lane & 15;
    const int wm   = wave & 1;
    const int wn   = wave >> 1;
    const int srow = t >> 2;
    const int scol = (t & 3) * 8;
    const int ldsoff = wave * 64 * 16;

    const int xcd   = blockIdx.x & 7;
    const int rank0 = blockIdx.x >> 3;
    const int* xst  = meta + (EPI == 0 ? 64 : 128) + xcd * 8;
    const int  Tx   = xst[4];

    for (int r = rank0; r < Tx; r += 256) {
        const int k3 = (r >= xst[1]) + (r >= xst[2]) + (r >= xst[3]);
        const int e = 3 - k3;
        const int rl = r - xst[k3];
        const int mtiles = meta[12 + e];

        int mt, nt;
        if (EPI == 0) {
            const int q = ((H >> (3 - e)) >> 7) >> 3;   // ntiles1/8 (4,2,1,0)
            if (q) { mt = rl / q; nt = xcd * q + (rl - mt * q); }
            else   { const int m0 = mtiles >> 1;        // e0: 4 N-panels, 2 XCDs each
                     nt = xcd >> 1;
                     mt = (xcd & 1) ? (m0 + rl) : rl; }
        } else {
            const int qm = mtiles >> 3, rm = mtiles & 7;
            const int cm = qm + ((xcd < rm) ? 1 : 0);
            const int bm = xcd * qm + ((xcd < rm) ? xcd : rm);
            nt = rl / cm;
            mt = bm + (rl - nt * cm);
        }

        const int K   = (EPI == 0) ? (D >> (3 - e)) : (H >> (3 - e));
        const int Ne  = (EPI == 0) ? (H >> (3 - e)) : D;
        const int lda = K;
        const int ldb = (EPI == 0) ? D : H;
        const int nb  = nt * 128;
        const ushort_t* A = Abuf + (size_t)((EPI == 0) ? meta[16 + e] : meta[20 + e]);

        const ushort_t* Ag = A + (size_t)(mt * 128 + srow) * lda + scol;
        const ushort_t* Bg = Bw + (size_t)(nb + srow) * ldb + scol;

        const int nsteps = K >> 5;   // >= 4 (K >= 128)

        f32x4 acc[4][4] = {};

        // prologue: fill the 3-deep pipeline
        stage4(Ag,      Bg,      lda, ldb, (char*)As[0], (char*)Bs[0], ldsoff);
        stage4(Ag + 32, Bg + 32, lda, ldb, (char*)As[1], (char*)Bs[1], ldsoff);
        stage4(Ag + 64, Bg + 64, lda, ldb, (char*)As[2], (char*)Bs[2], ldsoff);

        int cur = 0;
        for (int s = 0; s < nsteps; ++s) {
            const int rem = nsteps - s;
            if (rem > 2)       { asm volatile("s_waitcnt vmcnt(8)" ::: "memory"); }
            else if (rem == 2) { asm volatile("s_waitcnt vmcnt(4)" ::: "memory"); }
            else               { asm volatile("s_waitcnt vmcnt(0)" ::: "memory"); }
            __builtin_amdgcn_s_barrier();        // all waves' step-s loads landed
            asm volatile("" ::: "memory");

            bf16x8 af[4], bfr[4];
#pragma unroll
            for (int i = 0; i < 4; i++) {
                af[i]  = *(const bf16x8*)(As[cur] + (wm * 64 + i * 16 + l16) * 32 + quad * 8);
                bfr[i] = *(const bf16x8*)(Bs[cur] + (wn * 64 + i * 16 + l16) * 32 + quad * 8);
            }
            asm volatile("s_waitcnt lgkmcnt(0)" ::: "memory");  // this wave done reading
            __builtin_amdgcn_s_barrier();        // all waves done reading buf[cur]
            asm volatile("" ::: "memory");

            if (s + 3 < nsteps)
                stage4(Ag + (size_t)(s + 3) * 32, Bg + (size_t)(s + 3) * 32,
                       lda, ldb, (char*)As[cur], (char*)Bs[cur], ldsoff);

#pragma unroll
            for (int i = 0; i < 4; i++)
#pragma unroll
                for (int j = 0; j < 4; j++)
                    acc[i][j] = __builtin_amdgcn_mfma_f32_16x16x32_bf16(af[i], bfr[j], acc[i][j], 0, 0, 0);

            cur = (cur == 2) ? 0 : cur + 1;
        }

        // epilogue: C/D layout col=lane&15, row=quad*4+reg
        const int colbase = nb + wn * 64 + l16;
        float bv[4];
#pragma unroll
        for (int j = 0; j < 4; j++) bv[j] = bias[colbase + j * 16];

#pragma unroll
        for (int i = 0; i < 4; i++) {
#pragma unroll
            for (int r2 = 0; r2 < 4; r2++) {
                const int lrow = mt * 128 + wm * 64 + i * 16 + quad * 4 + r2;
                if (EPI == 0) {
                    ushort_t* dst = hb + (size_t)meta[20 + e] + (size_t)lrow * Ne;
#pragma unroll
                    for (int j = 0; j < 4; j++)
                        dst[colbase + j * 16] = f2bf(gelu_fast(acc[i][j][r2] + bv[j]));
                } else {
                    const int tok = sidx[meta[4 + e] + lrow];
                    if (tok >= 0) {
                        float* dst = out + (size_t)tok * D;
#pragma unroll
                        for (int j = 0; j < 4; j++)
                            dst[colbase + j * 16] = acc[i][j][r2] + bv[j];
                    }
                }
            }
        }
        // last step's read-done barrier protects LDS; next tile's prologue loads
        // retire in-order behind it.
    }
}

// ---------------- fallback: naive fp32 per-token ----------------
__global__ void naive_kernel(const float* __restrict__ x, const int* __restrict__ tm,
                             const float* __restrict__ W1, const float* __restrict__ b1,
                             const float* __restrict__ W2, const float* __restrict__ b2,
                             float* __restrict__ out, int D, int Hdim) {
    const int t = blockIdx.x;
    const int m = tm[t];
    const int din = D >> (3 - m);
    const int dh = Hdim >> (3 - m);
    extern __shared__ float sm[];
    float* xs = sm;
    float* hs = sm + D;
    for (int i = threadIdx.x; i < din; i += blockDim.x) xs[i] = x[(size_t)t * D + i];
    __syncthreads();
    for (int h = threadIdx.x; h < dh; h += blockDim.x) {
        const float* w = W1 + (size_t)h * D;
        float a = b1[h];
        for (int d = 0; d < din; d++) a += xs[d] * w[d];
        hs[h] = gelu_exact(a);
    }
    __syncthreads();
    for (int d = threadIdx.x; d < D; d += blockDim.x) {
        const float* w = W2 + (size_t)d * Hdim;
        float a = b2[d];
        for (int h = 0; h < dh; h++) a += hs[h] * w[h];
        out[(size_t)t * D + d] = a;
    }
}

extern "C" void kernel_launch(void* const* d_in, const int* in_sizes, int n_in,
                              void* d_out, int out_size, void* d_ws, size_t ws_size,
                              hipStream_t stream) {
    const float* x  = (const float*)d_in[0];
    const int* tm   = (const int*)d_in[1];
    const float* W1 = (const float*)d_in[2];
    const float* b1 = (const float*)d_in[3];
    const float* W2 = (const float*)d_in[4];
    const float* b2 = (const float*)d_in[5];
    float* out = (float*)d_out;

    const int M    = in_sizes[1];
    const int Hdim = in_sizes[3];
    const int D    = in_sizes[0] / M;

    const int Mpad = M + 512;
    const int nchunks = M / 256;
    const size_t meta_sz = 1024;
    const size_t cnt_sz  = ((size_t)nchunks * 4 * 4 + 255) & ~(size_t)255;
    const size_t sidx_sz = ((size_t)Mpad * 4 + 255) & ~(size_t)255;
    const size_t xb_sz   = (size_t)Mpad * D * 2;
    const size_t w1_sz   = (size_t)Hdim * D * 2;
    const size_t w2_sz   = (size_t)D * Hdim * 2;
    const size_t hb_sz   = (size_t)Mpad * Hdim * 2;
    const size_t need_sorted = meta_sz + cnt_sz + sidx_sz + xb_sz + w1_sz + w2_sz + hb_sz;

    const bool shape_ok = (M % 256 == 0) && (D % 128 == 0) && (Hdim % 128 == 0) &&
                          (D >= 1024) && (D <= 1024) && (Hdim >= 4096);

    if (shape_ok && ws_size >= need_sorted) {
        char* p = (char*)d_ws;
        int* meta     = (int*)p;        p += meta_sz;
        int* cnt      = (int*)p;        p += cnt_sz;
        int* sidx     = (int*)p;        p += sidx_sz;
        ushort_t* xb  = (ushort_t*)p;   p += xb_sz;
        ushort_t* w1b = (ushort_t*)p;   p += w1_sz;
        ushort_t* w2b = (ushort_t*)p;   p += w2_sz;
        ushort_t* hb  = (ushort_t*)p;

        const int n4w = Hdim * D / 4;
        histo_convw_kernel<<<nchunks + 2048, 256, 0, stream>>>(tm, cnt, nchunks,
                                                               W1, W2, w1b, w2b, n4w);
        meta_kernel<<<1, 256, 0, stream>>>(meta, cnt, sidx, nchunks, D, Hdim);
        place_kernel<<<nchunks, 256, 0, stream>>>(tm, cnt, sidx);
        convert_x_sorted<<<2048, 256, 0, stream>>>(x, meta, sidx, xb, D);

        gemm_sorted<0><<<2048, 256, 0, stream>>>(xb, w1b, b1, meta, sidx, hb, nullptr, D, Hdim);
        gemm_sorted<1><<<2048, 256, 0, stream>>>(hb, w2b, b2, meta, sidx, nullptr, out, D, Hdim);
        return;
    }

    const size_t shmem = (size_t)(D + Hdim) * sizeof(float);
    naive_kernel<<<M, 256, shmem, stream>>>(x, tm, W1, b1, W2, b2, out, D, Hdim);
}